// Round 1
// baseline (1224.866 us; speedup 1.0000x reference)
//
#include <hip/hip_runtime.h>
#include <hip/hip_bf16.h>

// Problem constants
// B=8, H=W=64, N=4096, VA_IN=256, VB_IN=128, VC_IN=64, VOUT=128, R0=2, R1=4

__device__ __forceinline__ void gemm4x4(const float* __restrict__ Wg, int ldw, int o0,
                                        const float* __restrict__ Xs, int t0, int K,
                                        float (&acc)[4][4]) {
  for (int k0 = 0; k0 < K; k0 += 4) {
    float x[4][4];
#pragma unroll
    for (int kk = 0; kk < 4; ++kk) {
      const float4 v = *(const float4*)(Xs + (k0 + kk) * 32 + t0);
      x[kk][0] = v.x; x[kk][1] = v.y; x[kk][2] = v.z; x[kk][3] = v.w;
    }
#pragma unroll
    for (int i = 0; i < 4; ++i) {
      const float4 w = *(const float4*)(Wg + (size_t)(o0 + i) * ldw + k0);
#pragma unroll
      for (int j = 0; j < 4; ++j)
        acc[i][j] += w.x * x[0][j] + w.y * x[1][j] + w.z * x[2][j] + w.w * x[3][j];
    }
  }
}

__device__ __forceinline__ void gemm8x4(const float* __restrict__ Wg, int ldw, int o0,
                                        const float* __restrict__ Xs, int t0, int K,
                                        float (&acc)[8][4]) {
  for (int k0 = 0; k0 < K; k0 += 4) {
    float x[4][4];
#pragma unroll
    for (int kk = 0; kk < 4; ++kk) {
      const float4 v = *(const float4*)(Xs + (k0 + kk) * 32 + t0);
      x[kk][0] = v.x; x[kk][1] = v.y; x[kk][2] = v.z; x[kk][3] = v.w;
    }
#pragma unroll
    for (int i = 0; i < 8; ++i) {
      const float4 w = *(const float4*)(Wg + (size_t)(o0 + i) * ldw + k0);
#pragma unroll
      for (int j = 0; j < 4; ++j)
        acc[i][j] += w.x * x[0][j] + w.y * x[1][j] + w.z * x[2][j] + w.w * x[3][j];
    }
  }
}

// Kernel A: emb_a (2-layer MLP), gates, and proj_ab/proj_ac = W_ab[:128].emb_a
__global__ __launch_bounds__(256) void k_embA(
    const float* __restrict__ va, const float* __restrict__ Wa1,
    const float* __restrict__ Wa2, const float* __restrict__ Wgb,
    const float* __restrict__ Wgc, const float* __restrict__ Wab,
    const float* __restrict__ Wac,
    float* __restrict__ emb_a, float* __restrict__ gate_b, float* __restrict__ gate_c,
    float* __restrict__ proj_ab, float* __restrict__ proj_ac) {
  __shared__ float Xs[256 * 32];
  __shared__ float Hs[128 * 32];
  __shared__ float Pab[32 * 32];
  __shared__ float Pac[32 * 32];
  const int u = threadIdx.x;
  const int b = blockIdx.x >> 7, tile = blockIdx.x & 127;
  const int n0 = tile * 32;

  const float* xsrc = va + (size_t)b * 256 * 4096 + n0;
  for (int it = 0; it < 32; ++it) {
    int idx = u + it * 256;
    int row = idx >> 5, col = idx & 31;
    Xs[idx] = xsrc[(size_t)row * 4096 + col];
  }
  __syncthreads();

  const int og = u >> 3, o0 = og * 4, t0 = (u & 7) * 4;

  // H = relu(W_a1 @ X)
  float a1[4][4];
#pragma unroll
  for (int i = 0; i < 4; ++i)
#pragma unroll
    for (int j = 0; j < 4; ++j) a1[i][j] = 0.f;
  gemm4x4(Wa1, 256, o0, Xs, t0, 256, a1);
#pragma unroll
  for (int i = 0; i < 4; ++i)
#pragma unroll
    for (int j = 0; j < 4; ++j) Hs[(o0 + i) * 32 + t0 + j] = fmaxf(a1[i][j], 0.f);
  __syncthreads();

  // E = W_a2 @ H
  float a2[4][4];
#pragma unroll
  for (int i = 0; i < 4; ++i)
#pragma unroll
    for (int j = 0; j < 4; ++j) a2[i][j] = 0.f;
  gemm4x4(Wa2, 128, o0, Hs, t0, 128, a2);

  float* ea = emb_a + ((size_t)b * 128) * 4096 + n0;
#pragma unroll
  for (int i = 0; i < 4; ++i)
    *(float4*)(ea + (size_t)(o0 + i) * 4096 + t0) =
        make_float4(a2[i][0], a2[i][1], a2[i][2], a2[i][3]);
#pragma unroll
  for (int j = 0; j < 4; ++j) {
    float sab = 0.f, sac = 0.f;
#pragma unroll
    for (int i = 0; i < 4; ++i) {
      sab += Wab[o0 + i] * a2[i][j];
      sac += Wac[o0 + i] * a2[i][j];
    }
    Pab[og * 32 + t0 + j] = sab;
    Pac[og * 32 + t0 + j] = sac;
  }
  __syncthreads();
  if (u < 32) {
    float sab = 0.f, sac = 0.f;
    for (int g = 0; g < 32; ++g) { sab += Pab[g * 32 + u]; sac += Pac[g * 32 + u]; }
    proj_ab[b * 4096 + n0 + u] = sab;
    proj_ac[b * 4096 + n0 + u] = sac;
  }

  // gate_b = 1 - sigmoid(W_gb @ X) = 1/(1+exp(z))
  float ag[4][4];
#pragma unroll
  for (int i = 0; i < 4; ++i)
#pragma unroll
    for (int j = 0; j < 4; ++j) ag[i][j] = 0.f;
  gemm4x4(Wgb, 256, o0, Xs, t0, 256, ag);
  float* gb = gate_b + ((size_t)b * 128) * 4096 + n0;
#pragma unroll
  for (int i = 0; i < 4; ++i) {
    float4 v;
    v.x = 1.f / (1.f + expf(ag[i][0]));
    v.y = 1.f / (1.f + expf(ag[i][1]));
    v.z = 1.f / (1.f + expf(ag[i][2]));
    v.w = 1.f / (1.f + expf(ag[i][3]));
    *(float4*)(gb + (size_t)(o0 + i) * 4096 + t0) = v;
  }
#pragma unroll
  for (int i = 0; i < 4; ++i)
#pragma unroll
    for (int j = 0; j < 4; ++j) ag[i][j] = 0.f;
  gemm4x4(Wgc, 256, o0, Xs, t0, 256, ag);
  float* gc = gate_c + ((size_t)b * 128) * 4096 + n0;
#pragma unroll
  for (int i = 0; i < 4; ++i) {
    float4 v;
    v.x = 1.f / (1.f + expf(ag[i][0]));
    v.y = 1.f / (1.f + expf(ag[i][1]));
    v.z = 1.f / (1.f + expf(ag[i][2]));
    v.w = 1.f / (1.f + expf(ag[i][3]));
    *(float4*)(gc + (size_t)(o0 + i) * 4096 + t0) = v;
  }
}

// Fused attend: unfold -> 2-layer MLP -> logit -> online softmax over patches -> gated agg
// R: patch side (2 or 4); KIN: input channels (128 or 64)
template <int R, int KIN>
__global__ __launch_bounds__(256) void k_attend(
    const float* __restrict__ vsrc,  // [B][KIN][64R][64R]
    const float* __restrict__ W1,    // [128][KIN]
    const float* __restrict__ W2,    // [128][128]
    const float* __restrict__ Wrw,   // [256] (first 128: emb_a part, last 128: emb_p part)
    const float* __restrict__ proj,  // [B][4096]
    const float* __restrict__ gate,  // [B][128][4096]
    float* __restrict__ agg) {
  __shared__ float Vs[KIN * 32];
  __shared__ float Hs[128 * 32];
  __shared__ float Es[128 * 32];
  __shared__ float s_al[32], s_w[32], s_li[32];
  const int u = threadIdx.x;
  const int b = blockIdx.x >> 7, tile = blockIdx.x & 127;
  const int n0 = tile * 32;
  const int h = n0 >> 6, w0 = n0 & 63;
  const int og = u >> 3, o0 = og * 4, t0 = (u & 7) * 4;
  const int tt = u & 31, cg = u >> 5;
  const size_t HRW = (size_t)(64 * R) * (64 * R);

  float m = -INFINITY, l = 0.f;
  const float pa = (u < 32) ? proj[b * 4096 + n0 + u] : 0.f;
  float acc[16];
#pragma unroll
  for (int i = 0; i < 16; ++i) acc[i] = 0.f;

  for (int r = 0; r < R * R; ++r) {
    const int kh = r / R, kw = r % R;
    const float* vb = vsrc + (size_t)b * KIN * HRW + (size_t)(h * R + kh) * (64 * R) +
                      (size_t)w0 * R + kw;
    for (int it = 0; it < KIN * 32 / 256; ++it) {
      int idx = u + it * 256;
      int ci = idx >> 5, t = idx & 31;
      Vs[idx] = vb[(size_t)ci * HRW + (size_t)t * R];
    }
    __syncthreads();

    float a1[4][4];
#pragma unroll
    for (int i = 0; i < 4; ++i)
#pragma unroll
      for (int j = 0; j < 4; ++j) a1[i][j] = 0.f;
    gemm4x4(W1, KIN, o0, Vs, t0, KIN, a1);
#pragma unroll
    for (int i = 0; i < 4; ++i)
#pragma unroll
      for (int j = 0; j < 4; ++j) Hs[(o0 + i) * 32 + t0 + j] = fmaxf(a1[i][j], 0.f);
    __syncthreads();

    float a2[4][4];
#pragma unroll
    for (int i = 0; i < 4; ++i)
#pragma unroll
      for (int j = 0; j < 4; ++j) a2[i][j] = 0.f;
    gemm4x4(W2, 128, o0, Hs, t0, 128, a2);
#pragma unroll
    for (int i = 0; i < 4; ++i)
#pragma unroll
      for (int j = 0; j < 4; ++j) Es[(o0 + i) * 32 + t0 + j] = a2[i][j];
    __syncthreads();

    if (u < 32) {
      float pe = 0.f;
      for (int c = 0; c < 128; ++c) pe += Wrw[128 + c] * Es[c * 32 + u];
      float logit = fmaxf(pa + pe, 0.f);
      float mnew = fmaxf(m, logit);
      float alpha = expf(m - mnew);
      float wexp = expf(logit - mnew);
      l = l * alpha + wexp;
      m = mnew;
      s_al[u] = alpha;
      s_w[u] = wexp;
    }
    __syncthreads();

    const float al = s_al[tt], wc = s_w[tt];
#pragma unroll
    for (int i = 0; i < 16; ++i)
      acc[i] = acc[i] * al + wc * Es[(cg * 16 + i) * 32 + tt];
    __syncthreads();
  }

  if (u < 32) s_li[u] = 1.f / l;
  __syncthreads();
  const float li = s_li[tt];
#pragma unroll
  for (int i = 0; i < 16; ++i) {
    int c = cg * 16 + i;
    size_t idx = ((size_t)(b * 128 + c)) * 4096 + n0 + tt;
    agg[idx] = acc[i] * li * gate[idx];
  }
}

// Kernel D: agg = sigmoid(concat) ; y = relu(W_r1 @ agg) ; out = W_r2 @ y
__global__ __launch_bounds__(256) void k_final(
    const float* __restrict__ agg_b, const float* __restrict__ agg_c,
    const float* __restrict__ emb_a, const float* __restrict__ Wr1,
    const float* __restrict__ Wr2, float* __restrict__ out) {
  __shared__ float S[384 * 32];  // A tile, reused for Y tile
  const int u = threadIdx.x;
  const int b = blockIdx.x >> 7, tile = blockIdx.x & 127;
  const int n0 = tile * 32;

  for (int it = 0; it < 48; ++it) {
    int idx = u + it * 256;
    int row = idx >> 5, t = idx & 31;
    const float* src = (row < 128) ? agg_b : ((row < 256) ? agg_c : emb_a);
    int c = row & 127;
    float v = src[((size_t)(b * 128 + c)) * 4096 + n0 + t];
    S[idx] = 1.f / (1.f + expf(-v));
  }
  __syncthreads();

  const int og = u >> 3, o0 = og * 8, t0 = (u & 7) * 4;
  float acc[8][4];
#pragma unroll
  for (int i = 0; i < 8; ++i)
#pragma unroll
    for (int j = 0; j < 4; ++j) acc[i][j] = 0.f;
  gemm8x4(Wr1, 384, o0, S, t0, 384, acc);
  __syncthreads();  // all reads of A done before overwriting with Y
#pragma unroll
  for (int i = 0; i < 8; ++i)
#pragma unroll
    for (int j = 0; j < 4; ++j) S[(o0 + i) * 32 + t0 + j] = fmaxf(acc[i][j], 0.f);
  __syncthreads();

#pragma unroll
  for (int i = 0; i < 8; ++i)
#pragma unroll
    for (int j = 0; j < 4; ++j) acc[i][j] = 0.f;
  gemm8x4(Wr2, 256, o0, S, t0, 256, acc);
#pragma unroll
  for (int i = 0; i < 8; ++i)
    *(float4*)(out + ((size_t)(b * 256 + o0 + i)) * 4096 + n0 + t0) =
        make_float4(acc[i][0], acc[i][1], acc[i][2], acc[i][3]);
}

extern "C" void kernel_launch(void* const* d_in, const int* in_sizes, int n_in,
                              void* d_out, int out_size, void* d_ws, size_t ws_size,
                              hipStream_t stream) {
  (void)in_sizes; (void)n_in; (void)out_size; (void)ws_size;
  const float* va  = (const float*)d_in[0];
  const float* vb  = (const float*)d_in[1];
  const float* vc  = (const float*)d_in[2];
  const float* Wa1 = (const float*)d_in[3];
  const float* Wa2 = (const float*)d_in[4];
  const float* Wgb = (const float*)d_in[5];
  const float* Wgc = (const float*)d_in[6];
  const float* Wb1 = (const float*)d_in[7];
  const float* Wb2 = (const float*)d_in[8];
  const float* Wc1 = (const float*)d_in[9];
  const float* Wc2 = (const float*)d_in[10];
  const float* Wab = (const float*)d_in[11];
  const float* Wac = (const float*)d_in[12];
  const float* Wr1 = (const float*)d_in[13];
  const float* Wr2 = (const float*)d_in[14];
  float* out = (float*)d_out;
  float* ws = (float*)d_ws;

  const size_t SZ = (size_t)8 * 128 * 4096;
  float* emb_a  = ws;
  float* gate_b = ws + SZ;
  float* gate_c = ws + 2 * SZ;
  float* agg_b  = ws + 3 * SZ;
  float* agg_c  = ws + 4 * SZ;
  float* proj_ab = ws + 5 * SZ;
  float* proj_ac = proj_ab + 8 * 4096;

  dim3 blk(256);
  k_embA<<<1024, blk, 0, stream>>>(va, Wa1, Wa2, Wgb, Wgc, Wab, Wac,
                                   emb_a, gate_b, gate_c, proj_ab, proj_ac);
  k_attend<2, 128><<<1024, blk, 0, stream>>>(vb, Wb1, Wb2, Wab, proj_ab, gate_b, agg_b);
  k_attend<4, 64><<<1024, blk, 0, stream>>>(vc, Wc1, Wc2, Wac, proj_ac, gate_c, agg_c);
  k_final<<<1024, blk, 0, stream>>>(agg_b, agg_c, emb_a, Wr1, Wr2, out);
}

// Round 2
// 825.745 us; speedup vs baseline: 1.4833x; 1.4833x over previous
//
#include <hip/hip_runtime.h>
#include <hip/hip_bf16.h>

// Problem constants
// B=8, H=W=64, N=4096, VA_IN=256, VB_IN=128, VC_IN=64, VOUT=128, R0=2, R1=4

typedef __attribute__((ext_vector_type(8))) short bhalf8;
typedef __attribute__((ext_vector_type(4))) float f32x4;

__device__ __forceinline__ unsigned short f2b(float f) {
  union { float f; unsigned u; } v; v.f = f;
  unsigned r = v.u + 0x7FFFu + ((v.u >> 16) & 1u);  // RNE
  return (unsigned short)(r >> 16);
}
__device__ __forceinline__ float b2f(unsigned short h) {
  union { unsigned u; float f; } v; v.u = ((unsigned)h) << 16;
  return v.f;
}

__device__ __forceinline__ void gemm4x4(const float* __restrict__ Wg, int ldw, int o0,
                                        const float* __restrict__ Xs, int t0, int K,
                                        float (&acc)[4][4]) {
  for (int k0 = 0; k0 < K; k0 += 4) {
    float x[4][4];
#pragma unroll
    for (int kk = 0; kk < 4; ++kk) {
      const float4 v = *(const float4*)(Xs + (k0 + kk) * 32 + t0);
      x[kk][0] = v.x; x[kk][1] = v.y; x[kk][2] = v.z; x[kk][3] = v.w;
    }
#pragma unroll
    for (int i = 0; i < 4; ++i) {
      const float4 w = *(const float4*)(Wg + (size_t)(o0 + i) * ldw + k0);
#pragma unroll
      for (int j = 0; j < 4; ++j)
        acc[i][j] += w.x * x[0][j] + w.y * x[1][j] + w.z * x[2][j] + w.w * x[3][j];
    }
  }
}

__device__ __forceinline__ void gemm8x4(const float* __restrict__ Wg, int ldw, int o0,
                                        const float* __restrict__ Xs, int t0, int K,
                                        float (&acc)[8][4]) {
  for (int k0 = 0; k0 < K; k0 += 4) {
    float x[4][4];
#pragma unroll
    for (int kk = 0; kk < 4; ++kk) {
      const float4 v = *(const float4*)(Xs + (k0 + kk) * 32 + t0);
      x[kk][0] = v.x; x[kk][1] = v.y; x[kk][2] = v.z; x[kk][3] = v.w;
    }
#pragma unroll
    for (int i = 0; i < 8; ++i) {
      const float4 w = *(const float4*)(Wg + (size_t)(o0 + i) * ldw + k0);
#pragma unroll
      for (int j = 0; j < 4; ++j)
        acc[i][j] += w.x * x[0][j] + w.y * x[1][j] + w.z * x[2][j] + w.w * x[3][j];
    }
  }
}

// Prep: convert branch weights to bf16, compute wv = W2^T . Wrw[128:]
__global__ __launch_bounds__(256) void k_prep(
    const float* __restrict__ W1, const float* __restrict__ W2,
    const float* __restrict__ Wrw, int kin,
    unsigned short* __restrict__ W1b, unsigned short* __restrict__ W2b,
    float* __restrict__ wv) {
  const int u = threadIdx.x;
  for (int i = u; i < 128 * kin; i += 256) W1b[i] = f2b(W1[i]);
  for (int i = u; i < 128 * 128; i += 256) W2b[i] = f2b(W2[i]);
  if (u < 128) {
    float s = 0.f;
    for (int c = 0; c < 128; ++c) s += Wrw[128 + c] * W2[c * 128 + u];
    wv[u] = s;
  }
}

// Kernel A: emb_a (2-layer MLP), gates, and proj_ab/proj_ac = W_ab[:128].emb_a
__global__ __launch_bounds__(256) void k_embA(
    const float* __restrict__ va, const float* __restrict__ Wa1,
    const float* __restrict__ Wa2, const float* __restrict__ Wgb,
    const float* __restrict__ Wgc, const float* __restrict__ Wab,
    const float* __restrict__ Wac,
    float* __restrict__ emb_a, float* __restrict__ gate_b, float* __restrict__ gate_c,
    float* __restrict__ proj_ab, float* __restrict__ proj_ac) {
  __shared__ float Xs[256 * 32];
  __shared__ float Hs[128 * 32];
  __shared__ float Pab[32 * 32];
  __shared__ float Pac[32 * 32];
  const int u = threadIdx.x;
  const int b = blockIdx.x >> 7, tile = blockIdx.x & 127;
  const int n0 = tile * 32;

  const float* xsrc = va + (size_t)b * 256 * 4096 + n0;
  for (int it = 0; it < 32; ++it) {
    int idx = u + it * 256;
    int row = idx >> 5, col = idx & 31;
    Xs[idx] = xsrc[(size_t)row * 4096 + col];
  }
  __syncthreads();

  const int og = u >> 3, o0 = og * 4, t0 = (u & 7) * 4;

  float a1[4][4];
#pragma unroll
  for (int i = 0; i < 4; ++i)
#pragma unroll
    for (int j = 0; j < 4; ++j) a1[i][j] = 0.f;
  gemm4x4(Wa1, 256, o0, Xs, t0, 256, a1);
#pragma unroll
  for (int i = 0; i < 4; ++i)
#pragma unroll
    for (int j = 0; j < 4; ++j) Hs[(o0 + i) * 32 + t0 + j] = fmaxf(a1[i][j], 0.f);
  __syncthreads();

  float a2[4][4];
#pragma unroll
  for (int i = 0; i < 4; ++i)
#pragma unroll
    for (int j = 0; j < 4; ++j) a2[i][j] = 0.f;
  gemm4x4(Wa2, 128, o0, Hs, t0, 128, a2);

  float* ea = emb_a + ((size_t)b * 128) * 4096 + n0;
#pragma unroll
  for (int i = 0; i < 4; ++i)
    *(float4*)(ea + (size_t)(o0 + i) * 4096 + t0) =
        make_float4(a2[i][0], a2[i][1], a2[i][2], a2[i][3]);
#pragma unroll
  for (int j = 0; j < 4; ++j) {
    float sab = 0.f, sac = 0.f;
#pragma unroll
    for (int i = 0; i < 4; ++i) {
      sab += Wab[o0 + i] * a2[i][j];
      sac += Wac[o0 + i] * a2[i][j];
    }
    Pab[og * 32 + t0 + j] = sab;
    Pac[og * 32 + t0 + j] = sac;
  }
  __syncthreads();
  if (u < 32) {
    float sab = 0.f, sac = 0.f;
    for (int g = 0; g < 32; ++g) { sab += Pab[g * 32 + u]; sac += Pac[g * 32 + u]; }
    proj_ab[b * 4096 + n0 + u] = sab;
    proj_ac[b * 4096 + n0 + u] = sac;
  }

  float ag[4][4];
#pragma unroll
  for (int i = 0; i < 4; ++i)
#pragma unroll
    for (int j = 0; j < 4; ++j) ag[i][j] = 0.f;
  gemm4x4(Wgb, 256, o0, Xs, t0, 256, ag);
  float* gb = gate_b + ((size_t)b * 128) * 4096 + n0;
#pragma unroll
  for (int i = 0; i < 4; ++i) {
    float4 v;
    v.x = 1.f / (1.f + expf(ag[i][0]));
    v.y = 1.f / (1.f + expf(ag[i][1]));
    v.z = 1.f / (1.f + expf(ag[i][2]));
    v.w = 1.f / (1.f + expf(ag[i][3]));
    *(float4*)(gb + (size_t)(o0 + i) * 4096 + t0) = v;
  }
#pragma unroll
  for (int i = 0; i < 4; ++i)
#pragma unroll
    for (int j = 0; j < 4; ++j) ag[i][j] = 0.f;
  gemm4x4(Wgc, 256, o0, Xs, t0, 256, ag);
  float* gc = gate_c + ((size_t)b * 128) * 4096 + n0;
#pragma unroll
  for (int i = 0; i < 4; ++i) {
    float4 v;
    v.x = 1.f / (1.f + expf(ag[i][0]));
    v.y = 1.f / (1.f + expf(ag[i][1]));
    v.z = 1.f / (1.f + expf(ag[i][2]));
    v.w = 1.f / (1.f + expf(ag[i][3]));
    *(float4*)(gc + (size_t)(o0 + i) * 4096 + t0) = v;
  }
}

// MFMA attend: unfold -> MLP(16x16x32 bf16 MFMA) -> logit(wv.H) -> softmax over
// patches -> gated weighted sum. Columns = token*P + patch (128 per block).
template <int R, int KIN>
__global__ __launch_bounds__(256) void k_attend_mfma(
    const float* __restrict__ vsrc,            // [B][KIN][64R][64R]
    const unsigned short* __restrict__ W1b,    // [128][KIN] bf16
    const unsigned short* __restrict__ W2b,    // [128][128] bf16
    const float* __restrict__ wv,              // [128] = W2^T . Wrw_p
    const float* __restrict__ proj,            // [B][4096]
    const float* __restrict__ gate,            // [B][128][4096]
    float* __restrict__ agg) {
  constexpr int P = R * R;          // patches/token
  constexpr int T = 128 / P;        // tokens/block
  constexpr int K1 = KIN / 32;      // layer-1 MFMA k-steps
  constexpr int PV = KIN + 8;       // Vs pitch (bf16)
  constexpr int PH = 136;           // Hs/Es pitch (bf16)
  constexpr int HR = 64 * R;
  constexpr int TILES = 4096 / T;
  constexpr int LOG2T = (T == 8) ? 3 : 5;

  __shared__ unsigned short smem[128 * (PV + PH)];
  unsigned short* Vs = smem;
  unsigned short* Hs = smem + 128 * PV;
  unsigned short* Es = smem;  // overlay: written only after all V/H reads complete
  __shared__ float s_logit[128];
  __shared__ float s_wgt[128];

  const int u = threadIdx.x;
  const int b = blockIdx.x / TILES;
  const int tile = blockIdx.x % TILES;
  const int n0 = tile * T;
  const int h = n0 >> 6, w0 = n0 & 63;
  const size_t HRW = (size_t)HR * HR;
  const float* vb = vsrc + (size_t)b * KIN * HRW;

  // ---- stage V tile as bf16 in B-fragment-friendly [col][k] layout ----
#pragma unroll
  for (int i = 0; i < KIN / 4; ++i) {
    int idx = i * 256 + u;
    int col = idx & 127;
    int kp = idx >> 7;           // k-pair
    int t = col / P, r = col & (P - 1);
    int kh = r / R, kw = r & (R - 1);
    int hp = h * R + kh;
    int wp = (w0 + t) * R + kw;
    size_t base = (size_t)(2 * kp) * HRW + (size_t)hp * HR + wp;
    float f0 = vb[base];
    float f1 = vb[base + HRW];
    unsigned pk = (unsigned)f2b(f0) | ((unsigned)f2b(f1) << 16);
    *(unsigned*)(Vs + col * PV + 2 * kp) = pk;
  }
  __syncthreads();

  const int wave = u >> 6, lane = u & 63, quad = lane >> 4, ln = lane & 15;
  const int ct0 = wave * 2;

  // ---- layer 1: H = relu(W1 @ V) ----
  bhalf8 bf1[2][K1];
#pragma unroll
  for (int c2 = 0; c2 < 2; ++c2) {
    int col = (ct0 + c2) * 16 + ln;
#pragma unroll
    for (int ks = 0; ks < K1; ++ks)
      bf1[c2][ks] = *(const bhalf8*)(Vs + col * PV + ks * 32 + quad * 8);
  }
  f32x4 acc1[8][2];
#pragma unroll
  for (int rt = 0; rt < 8; ++rt)
#pragma unroll
    for (int c2 = 0; c2 < 2; ++c2) acc1[rt][c2] = (f32x4)(0.f);
#pragma unroll
  for (int rt = 0; rt < 8; ++rt) {
    bhalf8 af[K1];
#pragma unroll
    for (int ks = 0; ks < K1; ++ks)
      af[ks] = *(const bhalf8*)((const short*)W1b + (rt * 16 + ln) * KIN + ks * 32 + quad * 8);
#pragma unroll
    for (int c2 = 0; c2 < 2; ++c2)
#pragma unroll
      for (int ks = 0; ks < K1; ++ks)
        acc1[rt][c2] = __builtin_amdgcn_mfma_f32_16x16x32_bf16(af[ks], bf1[c2][ks],
                                                               acc1[rt][c2], 0, 0, 0);
  }
  // write H (relu, bf16) in [col][k] layout; C-layout gives 4 consecutive k
#pragma unroll
  for (int rt = 0; rt < 8; ++rt)
#pragma unroll
    for (int c2 = 0; c2 < 2; ++c2) {
      int col = (ct0 + c2) * 16 + ln;
      int k = rt * 16 + quad * 4;
      f32x4 v = acc1[rt][c2];
      unsigned u0 = (unsigned)f2b(fmaxf(v.x, 0.f)) | ((unsigned)f2b(fmaxf(v.y, 0.f)) << 16);
      unsigned u1 = (unsigned)f2b(fmaxf(v.z, 0.f)) | ((unsigned)f2b(fmaxf(v.w, 0.f)) << 16);
      *(unsigned*)(Hs + col * PH + k) = u0;
      *(unsigned*)(Hs + col * PH + k + 2) = u1;
    }
  __syncthreads();

  // ---- logit per column: relu(pa + wv . H[:,col]) ----
  if (u < 128) {
    float pa = proj[b * 4096 + n0 + (u / P)];
    float s = 0.f;
#pragma unroll 8
    for (int k = 0; k < 128; k += 2) {
      unsigned pk = *(const unsigned*)(Hs + u * PH + k);
      s += wv[k] * b2f((unsigned short)pk) + wv[k + 1] * b2f((unsigned short)(pk >> 16));
    }
    s_logit[u] = fmaxf(s + pa, 0.f);
  }

  // ---- layer 2: E = W2 @ H ----
  bhalf8 bf2[2][4];
#pragma unroll
  for (int c2 = 0; c2 < 2; ++c2) {
    int col = (ct0 + c2) * 16 + ln;
#pragma unroll
    for (int ks = 0; ks < 4; ++ks)
      bf2[c2][ks] = *(const bhalf8*)(Hs + col * PH + ks * 32 + quad * 8);
  }
  f32x4 acc2[8][2];
#pragma unroll
  for (int rt = 0; rt < 8; ++rt)
#pragma unroll
    for (int c2 = 0; c2 < 2; ++c2) acc2[rt][c2] = (f32x4)(0.f);
#pragma unroll
  for (int rt = 0; rt < 8; ++rt) {
    bhalf8 af[4];
#pragma unroll
    for (int ks = 0; ks < 4; ++ks)
      af[ks] = *(const bhalf8*)((const short*)W2b + (rt * 16 + ln) * 128 + ks * 32 + quad * 8);
#pragma unroll
    for (int c2 = 0; c2 < 2; ++c2)
#pragma unroll
      for (int ks = 0; ks < 4; ++ks)
        acc2[rt][c2] = __builtin_amdgcn_mfma_f32_16x16x32_bf16(af[ks], bf2[c2][ks],
                                                               acc2[rt][c2], 0, 0, 0);
  }
  __syncthreads();  // all H reads (MFMA2 + logit) done; Es may overwrite V/H

  // ---- write E (bf16) + softmax over patches ----
#pragma unroll
  for (int rt = 0; rt < 8; ++rt)
#pragma unroll
    for (int c2 = 0; c2 < 2; ++c2) {
      int col = (ct0 + c2) * 16 + ln;
      int k = rt * 16 + quad * 4;
      f32x4 v = acc2[rt][c2];
      unsigned u0 = (unsigned)f2b(v.x) | ((unsigned)f2b(v.y) << 16);
      unsigned u1 = (unsigned)f2b(v.z) | ((unsigned)f2b(v.w) << 16);
      *(unsigned*)(Es + col * PH + k) = u0;
      *(unsigned*)(Es + col * PH + k + 2) = u1;
    }
  if (u < T) {
    float e[P];
    float mx = -INFINITY;
#pragma unroll
    for (int r = 0; r < P; ++r) {
      e[r] = s_logit[u * P + r];
      mx = fmaxf(mx, e[r]);
    }
    float s = 0.f;
#pragma unroll
    for (int r = 0; r < P; ++r) {
      e[r] = expf(e[r] - mx);
      s += e[r];
    }
    float inv = 1.f / s;
#pragma unroll
    for (int r = 0; r < P; ++r) s_wgt[u * P + r] = e[r] * inv;
  }
  __syncthreads();

  // ---- agg[c][t] = (sum_r E[t*P+r][c] * wgt) * gate ----
#pragma unroll
  for (int i = 0; i < (T * 64) / 256; ++i) {
    int idx = i * 256 + u;
    int t = idx & (T - 1);
    int cp = idx >> LOG2T;  // channel pair 0..63
    float s0 = 0.f, s1 = 0.f;
#pragma unroll
    for (int r = 0; r < P; ++r) {
      int col = t * P + r;
      float w = s_wgt[col];
      unsigned pk = *(const unsigned*)(Es + col * PH + cp * 2);
      s0 += w * b2f((unsigned short)pk);
      s1 += w * b2f((unsigned short)(pk >> 16));
    }
    size_t o = ((size_t)(b * 128 + cp * 2)) * 4096 + n0 + t;
    agg[o] = s0 * gate[o];
    agg[o + 4096] = s1 * gate[o + 4096];
  }
}

// Kernel D: agg = sigmoid(concat) ; y = relu(W_r1 @ agg) ; out = W_r2 @ y
__global__ __launch_bounds__(256) void k_final(
    const float* __restrict__ agg_b, const float* __restrict__ agg_c,
    const float* __restrict__ emb_a, const float* __restrict__ Wr1,
    const float* __restrict__ Wr2, float* __restrict__ out) {
  __shared__ float S[384 * 32];
  const int u = threadIdx.x;
  const int b = blockIdx.x >> 7, tile = blockIdx.x & 127;
  const int n0 = tile * 32;

  for (int it = 0; it < 48; ++it) {
    int idx = u + it * 256;
    int row = idx >> 5, t = idx & 31;
    const float* src = (row < 128) ? agg_b : ((row < 256) ? agg_c : emb_a);
    int c = row & 127;
    float v = src[((size_t)(b * 128 + c)) * 4096 + n0 + t];
    S[idx] = 1.f / (1.f + expf(-v));
  }
  __syncthreads();

  const int og = u >> 3, o0 = og * 8, t0 = (u & 7) * 4;
  float acc[8][4];
#pragma unroll
  for (int i = 0; i < 8; ++i)
#pragma unroll
    for (int j = 0; j < 4; ++j) acc[i][j] = 0.f;
  gemm8x4(Wr1, 384, o0, S, t0, 384, acc);
  __syncthreads();
#pragma unroll
  for (int i = 0; i < 8; ++i)
#pragma unroll
    for (int j = 0; j < 4; ++j) S[(o0 + i) * 32 + t0 + j] = fmaxf(acc[i][j], 0.f);
  __syncthreads();

#pragma unroll
  for (int i = 0; i < 8; ++i)
#pragma unroll
    for (int j = 0; j < 4; ++j) acc[i][j] = 0.f;
  gemm8x4(Wr2, 256, o0, S, t0, 256, acc);
#pragma unroll
  for (int i = 0; i < 8; ++i)
    *(float4*)(out + ((size_t)(b * 256 + o0 + i)) * 4096 + n0 + t0) =
        make_float4(acc[i][0], acc[i][1], acc[i][2], acc[i][3]);
}

extern "C" void kernel_launch(void* const* d_in, const int* in_sizes, int n_in,
                              void* d_out, int out_size, void* d_ws, size_t ws_size,
                              hipStream_t stream) {
  (void)in_sizes; (void)n_in; (void)out_size; (void)ws_size;
  const float* va  = (const float*)d_in[0];
  const float* vb  = (const float*)d_in[1];
  const float* vc  = (const float*)d_in[2];
  const float* Wa1 = (const float*)d_in[3];
  const float* Wa2 = (const float*)d_in[4];
  const float* Wgb = (const float*)d_in[5];
  const float* Wgc = (const float*)d_in[6];
  const float* Wb1 = (const float*)d_in[7];
  const float* Wb2 = (const float*)d_in[8];
  const float* Wc1 = (const float*)d_in[9];
  const float* Wc2 = (const float*)d_in[10];
  const float* Wab = (const float*)d_in[11];
  const float* Wac = (const float*)d_in[12];
  const float* Wr1 = (const float*)d_in[13];
  const float* Wr2 = (const float*)d_in[14];
  float* out = (float*)d_out;
  float* ws = (float*)d_ws;

  const size_t SZ = (size_t)8 * 128 * 4096;
  float* emb_a   = ws;
  float* gate_b  = ws + SZ;
  float* gate_c  = ws + 2 * SZ;
  float* agg_b   = ws + 3 * SZ;
  float* agg_c   = ws + 4 * SZ;
  float* proj_ab = ws + 5 * SZ;
  float* proj_ac = proj_ab + 8 * 4096;
  float* wv_b    = proj_ac + 8 * 4096;
  float* wv_c    = wv_b + 128;
  unsigned short* W1b_b = (unsigned short*)(wv_c + 128);
  unsigned short* W2b_b = W1b_b + 128 * 128;
  unsigned short* W1b_c = W2b_b + 128 * 128;
  unsigned short* W2b_c = W1b_c + 128 * 64;

  dim3 blk(256);
  k_prep<<<1, blk, 0, stream>>>(Wb1, Wb2, Wab, 128, W1b_b, W2b_b, wv_b);
  k_prep<<<1, blk, 0, stream>>>(Wc1, Wc2, Wac, 64, W1b_c, W2b_c, wv_c);
  k_embA<<<1024, blk, 0, stream>>>(va, Wa1, Wa2, Wgb, Wgc, Wab, Wac,
                                   emb_a, gate_b, gate_c, proj_ab, proj_ac);
  k_attend_mfma<2, 128><<<8 * 128, blk, 0, stream>>>(vb, W1b_b, W2b_b, wv_b,
                                                     proj_ab, gate_b, agg_b);
  k_attend_mfma<4, 64><<<8 * 512, blk, 0, stream>>>(vc, W1b_c, W2b_c, wv_c,
                                                    proj_ac, gate_c, agg_c);
  k_final<<<1024, blk, 0, stream>>>(agg_b, agg_c, emb_a, Wr1, Wr2, out);
}

// Round 3
// 667.215 us; speedup vs baseline: 1.8358x; 1.2376x over previous
//
#include <hip/hip_runtime.h>
#include <hip/hip_bf16.h>

// Problem constants
// B=8, H=W=64, N=4096, VA_IN=256, VB_IN=128, VC_IN=64, VOUT=128, R0=2, R1=4

typedef __attribute__((ext_vector_type(8))) short bhalf8;
typedef __attribute__((ext_vector_type(4))) float f32x4;

__device__ __forceinline__ unsigned short f2b(float f) {
  union { float f; unsigned u; } v; v.f = f;
  unsigned r = v.u + 0x7FFFu + ((v.u >> 16) & 1u);  // RNE
  return (unsigned short)(r >> 16);
}
__device__ __forceinline__ float b2f(unsigned short h) {
  union { unsigned u; float f; } v; v.u = ((unsigned)h) << 16;
  return v.f;
}
__device__ __forceinline__ unsigned pk2(float a, float b) {
  return (unsigned)f2b(a) | ((unsigned)f2b(b) << 16);
}

// ---------------------------------------------------------------------------
// Prep: convert all weights to bf16; compute wv = W2^T . Wrw[128:]
// ---------------------------------------------------------------------------
__global__ __launch_bounds__(256) void k_prep_all(
    const float* __restrict__ Wa1, const float* __restrict__ Wa2,
    const float* __restrict__ Wgb, const float* __restrict__ Wgc,
    const float* __restrict__ Wb1, const float* __restrict__ Wb2,
    const float* __restrict__ Wc1, const float* __restrict__ Wc2,
    const float* __restrict__ Wr1, const float* __restrict__ Wr2,
    const float* __restrict__ Wab, const float* __restrict__ Wac,
    unsigned short* __restrict__ Wa1b, unsigned short* __restrict__ Wa2b,
    unsigned short* __restrict__ Wgbb, unsigned short* __restrict__ Wgcb,
    unsigned short* __restrict__ W1b_b, unsigned short* __restrict__ W2b_b,
    unsigned short* __restrict__ W1b_c, unsigned short* __restrict__ W2b_c,
    unsigned short* __restrict__ Wr1b, unsigned short* __restrict__ Wr2b,
    float* __restrict__ wv_b, float* __restrict__ wv_c) {
  const float* srcs[10] = {Wa1, Wa2, Wgb, Wgc, Wb1, Wb2, Wc1, Wc2, Wr1, Wr2};
  unsigned short* dsts[10] = {Wa1b, Wa2b, Wgbb, Wgcb, W1b_b, W2b_b, W1b_c, W2b_c, Wr1b, Wr2b};
  const int sizes[10] = {32768, 16384, 32768, 32768, 16384, 16384, 8192, 16384, 98304, 65536};
  int gid = blockIdx.x * 256 + threadIdx.x;
  int stride = gridDim.x * 256;
#pragma unroll
  for (int s = 0; s < 10; ++s)
    for (int i = gid; i < sizes[s]; i += stride) dsts[s][i] = f2b(srcs[s][i]);
  if (blockIdx.x == 0) {
    int u = threadIdx.x;
    if (u < 128) {
      float s = 0.f;
      for (int c = 0; c < 128; ++c) s += Wab[128 + c] * Wb2[c * 128 + u];
      wv_b[u] = s;
    } else {
      int v = u - 128;
      float s = 0.f;
      for (int c = 0; c < 128; ++c) s += Wac[128 + c] * Wc2[c * 128 + v];
      wv_c[v] = s;
    }
  }
}

// ---------------------------------------------------------------------------
// embA (MFMA): H=relu(Wa1@X); gates=1-sigmoid(Wg@X); E=Wa2@H; proj=Wab.E;
// Sa = sigmoid(E). Outputs token-major bf16. 64 tokens/block.
// ---------------------------------------------------------------------------
__global__ __launch_bounds__(256) void k_embA(
    const float* __restrict__ va,
    const unsigned short* __restrict__ Wa1b, const unsigned short* __restrict__ Wa2b,
    const unsigned short* __restrict__ Wgbb, const unsigned short* __restrict__ Wgcb,
    const float* __restrict__ Wab, const float* __restrict__ Wac,
    unsigned short* __restrict__ Sa, unsigned short* __restrict__ Gb,
    unsigned short* __restrict__ Gc,
    float* __restrict__ proj_ab, float* __restrict__ proj_ac) {
  constexpr int PX = 264, PHp = 136;
  __shared__ unsigned short Xs[64 * PX];   // 33.8 KB
  __shared__ unsigned short Hs[64 * PHp];  // 17.4 KB
  __shared__ float wabl[128], wacl[128];
  const int u = threadIdx.x;
  const int b = blockIdx.x >> 6, tile = blockIdx.x & 63;
  const int n0 = tile * 64;

  if (u < 128) wabl[u] = Wab[u];
  else wacl[u - 128] = Wac[u - 128];

  // stage X tile (256 ch x 64 tok) -> bf16 LDS [col][k]
  const float* xb = va + (size_t)b * 256 * 4096 + n0;
#pragma unroll
  for (int it = 0; it < 32; ++it) {
    int idx = it * 256 + u;
    int chp = idx >> 6, t = idx & 63;
    float f0 = xb[(size_t)(2 * chp) * 4096 + t];
    float f1 = xb[(size_t)(2 * chp + 1) * 4096 + t];
    *(unsigned*)(Xs + t * PX + 2 * chp) = pk2(f0, f1);
  }
  __syncthreads();

  const int wave = u >> 6, lane = u & 63, quad = lane >> 4, ln = lane & 15;
  const int col = wave * 16 + ln;
  const size_t tok = (size_t)(b * 4096 + n0 + col);

  bhalf8 bx[8];
#pragma unroll
  for (int ks = 0; ks < 8; ++ks)
    bx[ks] = *(const bhalf8*)(Xs + col * PX + ks * 32 + quad * 8);

  f32x4 acc[8];
  // ---- H = relu(Wa1 @ X) -> Hs (wave-local cols) ----
#pragma unroll
  for (int rt = 0; rt < 8; ++rt) acc[rt] = (f32x4)(0.f);
#pragma unroll
  for (int rt = 0; rt < 8; ++rt)
#pragma unroll
    for (int ks = 0; ks < 8; ++ks) {
      bhalf8 af = *(const bhalf8*)((const short*)Wa1b + (rt * 16 + ln) * 256 + ks * 32 + quad * 8);
      acc[rt] = __builtin_amdgcn_mfma_f32_16x16x32_bf16(af, bx[ks], acc[rt], 0, 0, 0);
    }
#pragma unroll
  for (int rt = 0; rt < 8; ++rt) {
    f32x4 v = acc[rt];
    uint2 p;
    p.x = pk2(fmaxf(v.x, 0.f), fmaxf(v.y, 0.f));
    p.y = pk2(fmaxf(v.z, 0.f), fmaxf(v.w, 0.f));
    *(uint2*)(Hs + col * PHp + rt * 16 + quad * 4) = p;
  }

  // ---- gate_b = 1/(1+exp(Wgb @ X)) ----
#pragma unroll
  for (int rt = 0; rt < 8; ++rt) acc[rt] = (f32x4)(0.f);
#pragma unroll
  for (int rt = 0; rt < 8; ++rt)
#pragma unroll
    for (int ks = 0; ks < 8; ++ks) {
      bhalf8 af = *(const bhalf8*)((const short*)Wgbb + (rt * 16 + ln) * 256 + ks * 32 + quad * 8);
      acc[rt] = __builtin_amdgcn_mfma_f32_16x16x32_bf16(af, bx[ks], acc[rt], 0, 0, 0);
    }
#pragma unroll
  for (int rt = 0; rt < 8; ++rt) {
    f32x4 v = acc[rt];
    uint2 p;
    p.x = pk2(1.f / (1.f + expf(v.x)), 1.f / (1.f + expf(v.y)));
    p.y = pk2(1.f / (1.f + expf(v.z)), 1.f / (1.f + expf(v.w)));
    *(uint2*)(Gb + tok * 128 + rt * 16 + quad * 4) = p;
  }

  // ---- gate_c ----
#pragma unroll
  for (int rt = 0; rt < 8; ++rt) acc[rt] = (f32x4)(0.f);
#pragma unroll
  for (int rt = 0; rt < 8; ++rt)
#pragma unroll
    for (int ks = 0; ks < 8; ++ks) {
      bhalf8 af = *(const bhalf8*)((const short*)Wgcb + (rt * 16 + ln) * 256 + ks * 32 + quad * 8);
      acc[rt] = __builtin_amdgcn_mfma_f32_16x16x32_bf16(af, bx[ks], acc[rt], 0, 0, 0);
    }
#pragma unroll
  for (int rt = 0; rt < 8; ++rt) {
    f32x4 v = acc[rt];
    uint2 p;
    p.x = pk2(1.f / (1.f + expf(v.x)), 1.f / (1.f + expf(v.y)));
    p.y = pk2(1.f / (1.f + expf(v.z)), 1.f / (1.f + expf(v.w)));
    *(uint2*)(Gc + tok * 128 + rt * 16 + quad * 4) = p;
  }

  // ---- E = Wa2 @ H (wave-local, no barrier needed) ----
  bhalf8 bh[4];
#pragma unroll
  for (int ks = 0; ks < 4; ++ks)
    bh[ks] = *(const bhalf8*)(Hs + col * PHp + ks * 32 + quad * 8);
#pragma unroll
  for (int rt = 0; rt < 8; ++rt) acc[rt] = (f32x4)(0.f);
#pragma unroll
  for (int rt = 0; rt < 8; ++rt)
#pragma unroll
    for (int ks = 0; ks < 4; ++ks) {
      bhalf8 af = *(const bhalf8*)((const short*)Wa2b + (rt * 16 + ln) * 128 + ks * 32 + quad * 8);
      acc[rt] = __builtin_amdgcn_mfma_f32_16x16x32_bf16(af, bh[ks], acc[rt], 0, 0, 0);
    }

  // proj + Sa = sigmoid(E)
  float pab = 0.f, pac = 0.f;
#pragma unroll
  for (int rt = 0; rt < 8; ++rt) {
    f32x4 v = acc[rt];
#pragma unroll
    for (int i = 0; i < 4; ++i) {
      float e = v[i];
      pab += wabl[rt * 16 + quad * 4 + i] * e;
      pac += wacl[rt * 16 + quad * 4 + i] * e;
    }
    uint2 p;
    p.x = pk2(1.f / (1.f + expf(-v.x)), 1.f / (1.f + expf(-v.y)));
    p.y = pk2(1.f / (1.f + expf(-v.z)), 1.f / (1.f + expf(-v.w)));
    *(uint2*)(Sa + tok * 128 + rt * 16 + quad * 4) = p;
  }
  pab += __shfl_xor(pab, 16, 64);
  pab += __shfl_xor(pab, 32, 64);
  pac += __shfl_xor(pac, 16, 64);
  pac += __shfl_xor(pac, 32, 64);
  if (lane < 16) {
    proj_ab[b * 4096 + n0 + col] = pab;
    proj_ac[b * 4096 + n0 + col] = pac;
  }
}

// ---------------------------------------------------------------------------
// MFMA attend: unfold -> MLP -> logit -> softmax over patches -> gated sum ->
// sigmoid -> token-major bf16 output.
// ---------------------------------------------------------------------------
template <int R, int KIN>
__global__ __launch_bounds__(256) void k_attend_mfma(
    const float* __restrict__ vsrc,            // [B][KIN][64R][64R]
    const unsigned short* __restrict__ W1b,    // [128][KIN] bf16
    const unsigned short* __restrict__ W2b,    // [128][128] bf16
    const float* __restrict__ wv,              // [128] = W2^T . Wrw_p
    const float* __restrict__ proj,            // [B][4096]
    const unsigned short* __restrict__ gate,   // [B][4096][128] bf16
    unsigned short* __restrict__ outS) {       // [B][4096][128] bf16
  constexpr int P = R * R;
  constexpr int T = 128 / P;
  constexpr int K1 = KIN / 32;
  constexpr int PV = KIN + 8;
  constexpr int PH = 136;
  constexpr int HR = 64 * R;
  constexpr int TILES = 4096 / T;

  __shared__ unsigned short smem[128 * (PV + PH)];
  unsigned short* Vs = smem;
  unsigned short* Hs = smem + 128 * PV;
  unsigned short* Es = smem;  // overlay after V/H dead
  __shared__ float s_logit[128];
  __shared__ float s_wgt[128];

  const int u = threadIdx.x;
  const int b = blockIdx.x / TILES;
  const int tile = blockIdx.x % TILES;
  const int n0 = tile * T;
  const int h = n0 >> 6, w0 = n0 & 63;
  const size_t HRW = (size_t)HR * HR;
  const float* vb = vsrc + (size_t)b * KIN * HRW;

#pragma unroll
  for (int i = 0; i < KIN / 4; ++i) {
    int idx = i * 256 + u;
    int col = idx & 127;
    int kp = idx >> 7;
    int t = col / P, r = col & (P - 1);
    int kh = r / R, kw = r & (R - 1);
    int hp = h * R + kh;
    int wp = (w0 + t) * R + kw;
    size_t base = (size_t)(2 * kp) * HRW + (size_t)hp * HR + wp;
    float f0 = vb[base];
    float f1 = vb[base + HRW];
    *(unsigned*)(Vs + col * PV + 2 * kp) = pk2(f0, f1);
  }
  __syncthreads();

  const int wave = u >> 6, lane = u & 63, quad = lane >> 4, ln = lane & 15;
  const int ct0 = wave * 2;

  // layer 1
  bhalf8 bf1[2][K1];
#pragma unroll
  for (int c2 = 0; c2 < 2; ++c2) {
    int col = (ct0 + c2) * 16 + ln;
#pragma unroll
    for (int ks = 0; ks < K1; ++ks)
      bf1[c2][ks] = *(const bhalf8*)(Vs + col * PV + ks * 32 + quad * 8);
  }
  f32x4 acc1[8][2];
#pragma unroll
  for (int rt = 0; rt < 8; ++rt)
#pragma unroll
    for (int c2 = 0; c2 < 2; ++c2) acc1[rt][c2] = (f32x4)(0.f);
#pragma unroll
  for (int rt = 0; rt < 8; ++rt) {
    bhalf8 af[K1];
#pragma unroll
    for (int ks = 0; ks < K1; ++ks)
      af[ks] = *(const bhalf8*)((const short*)W1b + (rt * 16 + ln) * KIN + ks * 32 + quad * 8);
#pragma unroll
    for (int c2 = 0; c2 < 2; ++c2)
#pragma unroll
      for (int ks = 0; ks < K1; ++ks)
        acc1[rt][c2] = __builtin_amdgcn_mfma_f32_16x16x32_bf16(af[ks], bf1[c2][ks],
                                                               acc1[rt][c2], 0, 0, 0);
  }
#pragma unroll
  for (int rt = 0; rt < 8; ++rt)
#pragma unroll
    for (int c2 = 0; c2 < 2; ++c2) {
      int col = (ct0 + c2) * 16 + ln;
      int k = rt * 16 + quad * 4;
      f32x4 v = acc1[rt][c2];
      *(unsigned*)(Hs + col * PH + k) = pk2(fmaxf(v.x, 0.f), fmaxf(v.y, 0.f));
      *(unsigned*)(Hs + col * PH + k + 2) = pk2(fmaxf(v.z, 0.f), fmaxf(v.w, 0.f));
    }
  __syncthreads();

  // logit per column
  if (u < 128) {
    float pa = proj[b * 4096 + n0 + (u / P)];
    float s = 0.f;
#pragma unroll 8
    for (int k = 0; k < 128; k += 2) {
      unsigned pkv = *(const unsigned*)(Hs + u * PH + k);
      s += wv[k] * b2f((unsigned short)pkv) + wv[k + 1] * b2f((unsigned short)(pkv >> 16));
    }
    s_logit[u] = fmaxf(s + pa, 0.f);
  }

  // layer 2
  bhalf8 bf2[2][4];
#pragma unroll
  for (int c2 = 0; c2 < 2; ++c2) {
    int col = (ct0 + c2) * 16 + ln;
#pragma unroll
    for (int ks = 0; ks < 4; ++ks)
      bf2[c2][ks] = *(const bhalf8*)(Hs + col * PH + ks * 32 + quad * 8);
  }
  f32x4 acc2[8][2];
#pragma unroll
  for (int rt = 0; rt < 8; ++rt)
#pragma unroll
    for (int c2 = 0; c2 < 2; ++c2) acc2[rt][c2] = (f32x4)(0.f);
#pragma unroll
  for (int rt = 0; rt < 8; ++rt) {
    bhalf8 af[4];
#pragma unroll
    for (int ks = 0; ks < 4; ++ks)
      af[ks] = *(const bhalf8*)((const short*)W2b + (rt * 16 + ln) * 128 + ks * 32 + quad * 8);
#pragma unroll
    for (int c2 = 0; c2 < 2; ++c2)
#pragma unroll
      for (int ks = 0; ks < 4; ++ks)
        acc2[rt][c2] = __builtin_amdgcn_mfma_f32_16x16x32_bf16(af[ks], bf2[c2][ks],
                                                               acc2[rt][c2], 0, 0, 0);
  }
  __syncthreads();  // all H reads done; Es may overwrite V/H

#pragma unroll
  for (int rt = 0; rt < 8; ++rt)
#pragma unroll
    for (int c2 = 0; c2 < 2; ++c2) {
      int col = (ct0 + c2) * 16 + ln;
      int k = rt * 16 + quad * 4;
      f32x4 v = acc2[rt][c2];
      *(unsigned*)(Es + col * PH + k) = pk2(v.x, v.y);
      *(unsigned*)(Es + col * PH + k + 2) = pk2(v.z, v.w);
    }
  if (u < T) {
    float e[P];
    float mx = -INFINITY;
#pragma unroll
    for (int r = 0; r < P; ++r) {
      e[r] = s_logit[u * P + r];
      mx = fmaxf(mx, e[r]);
    }
    float s = 0.f;
#pragma unroll
    for (int r = 0; r < P; ++r) {
      e[r] = expf(e[r] - mx);
      s += e[r];
    }
    float inv = 1.f / s;
#pragma unroll
    for (int r = 0; r < P; ++r) s_wgt[u * P + r] = e[r] * inv;
  }
  __syncthreads();

  constexpr int ITER2 = (T * 64) / 256;
#pragma unroll
  for (int i = 0; i < ITER2; ++i) {
    int idx = i * 256 + u;
    int cp = idx & 63;
    int t = idx >> 6;
    float s0 = 0.f, s1 = 0.f;
#pragma unroll
    for (int r = 0; r < P; ++r) {
      float w = s_wgt[t * P + r];
      unsigned pkv = *(const unsigned*)(Es + (t * P + r) * PH + 2 * cp);
      s0 += w * b2f((unsigned short)pkv);
      s1 += w * b2f((unsigned short)(pkv >> 16));
    }
    size_t tok = (size_t)(b * 4096 + n0 + t);
    unsigned gk = *(const unsigned*)(gate + tok * 128 + 2 * cp);
    float v0 = s0 * b2f((unsigned short)gk);
    float v1 = s1 * b2f((unsigned short)(gk >> 16));
    *(unsigned*)(outS + tok * 128 + 2 * cp) =
        pk2(1.f / (1.f + expf(-v0)), 1.f / (1.f + expf(-v1)));
  }
}

// ---------------------------------------------------------------------------
// Final (MFMA): S=[Sb|Sc|Sa] token-major bf16 (K=384); Y=relu(Wr1@S);
// out = Wr2 @ Y. 64 tokens/block, wave-local Y in LDS.
// ---------------------------------------------------------------------------
__global__ __launch_bounds__(256) void k_final(
    const unsigned short* __restrict__ Sb, const unsigned short* __restrict__ Sc,
    const unsigned short* __restrict__ Sa,
    const unsigned short* __restrict__ Wr1b, const unsigned short* __restrict__ Wr2b,
    float* __restrict__ out) {
  constexpr int PY = 264;
  __shared__ unsigned short Ys[64 * PY];  // 33.8 KB
  const int u = threadIdx.x;
  const int b = blockIdx.x >> 6, tile = blockIdx.x & 63;
  const int n0 = tile * 64;
  const int wave = u >> 6, lane = u & 63, quad = lane >> 4, ln = lane & 15;
  const int col = wave * 16 + ln;
  const size_t tok = (size_t)(b * 4096 + n0 + col);

  bhalf8 bs[12];
#pragma unroll
  for (int ks = 0; ks < 12; ++ks) {
    const unsigned short* S = (ks < 4) ? Sb : ((ks < 8) ? Sc : Sa);
    bs[ks] = *(const bhalf8*)(S + tok * 128 + (ks & 3) * 32 + quad * 8);
  }

  f32x4 acc[16];
#pragma unroll
  for (int rt = 0; rt < 16; ++rt) acc[rt] = (f32x4)(0.f);
#pragma unroll
  for (int rt = 0; rt < 16; ++rt)
#pragma unroll
    for (int ks = 0; ks < 12; ++ks) {
      bhalf8 af = *(const bhalf8*)((const short*)Wr1b + (rt * 16 + ln) * 384 + ks * 32 + quad * 8);
      acc[rt] = __builtin_amdgcn_mfma_f32_16x16x32_bf16(af, bs[ks], acc[rt], 0, 0, 0);
    }
#pragma unroll
  for (int rt = 0; rt < 16; ++rt) {
    f32x4 v = acc[rt];
    uint2 p;
    p.x = pk2(fmaxf(v.x, 0.f), fmaxf(v.y, 0.f));
    p.y = pk2(fmaxf(v.z, 0.f), fmaxf(v.w, 0.f));
    *(uint2*)(Ys + col * PY + rt * 16 + quad * 4) = p;
  }

  // wave-local: no barrier needed
  bhalf8 by[8];
#pragma unroll
  for (int ks = 0; ks < 8; ++ks)
    by[ks] = *(const bhalf8*)(Ys + col * PY + ks * 32 + quad * 8);
#pragma unroll
  for (int rt = 0; rt < 16; ++rt) acc[rt] = (f32x4)(0.f);
#pragma unroll
  for (int rt = 0; rt < 16; ++rt)
#pragma unroll
    for (int ks = 0; ks < 8; ++ks) {
      bhalf8 af = *(const bhalf8*)((const short*)Wr2b + (rt * 16 + ln) * 256 + ks * 32 + quad * 8);
      acc[rt] = __builtin_amdgcn_mfma_f32_16x16x32_bf16(af, by[ks], acc[rt], 0, 0, 0);
    }
#pragma unroll
  for (int rt = 0; rt < 16; ++rt) {
    f32x4 v = acc[rt];
#pragma unroll
    for (int i = 0; i < 4; ++i)
      out[((size_t)(b * 256 + rt * 16 + quad * 4 + i)) * 4096 + n0 + col] = v[i];
  }
}

extern "C" void kernel_launch(void* const* d_in, const int* in_sizes, int n_in,
                              void* d_out, int out_size, void* d_ws, size_t ws_size,
                              hipStream_t stream) {
  (void)in_sizes; (void)n_in; (void)out_size; (void)ws_size;
  const float* va  = (const float*)d_in[0];
  const float* vb  = (const float*)d_in[1];
  const float* vc  = (const float*)d_in[2];
  const float* Wa1 = (const float*)d_in[3];
  const float* Wa2 = (const float*)d_in[4];
  const float* Wgb = (const float*)d_in[5];
  const float* Wgc = (const float*)d_in[6];
  const float* Wb1 = (const float*)d_in[7];
  const float* Wb2 = (const float*)d_in[8];
  const float* Wc1 = (const float*)d_in[9];
  const float* Wc2 = (const float*)d_in[10];
  const float* Wab = (const float*)d_in[11];
  const float* Wac = (const float*)d_in[12];
  const float* Wr1 = (const float*)d_in[13];
  const float* Wr2 = (const float*)d_in[14];
  float* out = (float*)d_out;
  float* f = (float*)d_ws;

  const size_t SM = (size_t)8 * 4096 * 128 / 2;  // bf16 token-major array, in floats
  unsigned short* Sb = (unsigned short*)f; f += SM;
  unsigned short* Sc = (unsigned short*)f; f += SM;
  unsigned short* Sa = (unsigned short*)f; f += SM;
  unsigned short* Gb = (unsigned short*)f; f += SM;
  unsigned short* Gc = (unsigned short*)f; f += SM;
  float* proj_ab = f; f += 8 * 4096;
  float* proj_ac = f; f += 8 * 4096;
  float* wv_b = f; f += 128;
  float* wv_c = f; f += 128;
  unsigned short* Wa1b = (unsigned short*)f; f += 16384;
  unsigned short* Wa2b = (unsigned short*)f; f += 8192;
  unsigned short* Wgbb = (unsigned short*)f; f += 16384;
  unsigned short* Wgcb = (unsigned short*)f; f += 16384;
  unsigned short* W1b_b = (unsigned short*)f; f += 8192;
  unsigned short* W2b_b = (unsigned short*)f; f += 8192;
  unsigned short* W1b_c = (unsigned short*)f; f += 4096;
  unsigned short* W2b_c = (unsigned short*)f; f += 8192;
  unsigned short* Wr1b = (unsigned short*)f; f += 49152;
  unsigned short* Wr2b = (unsigned short*)f; f += 32768;

  dim3 blk(256);
  k_prep_all<<<120, blk, 0, stream>>>(Wa1, Wa2, Wgb, Wgc, Wb1, Wb2, Wc1, Wc2,
                                      Wr1, Wr2, Wab, Wac,
                                      Wa1b, Wa2b, Wgbb, Wgcb, W1b_b, W2b_b,
                                      W1b_c, W2b_c, Wr1b, Wr2b, wv_b, wv_c);
  k_embA<<<512, blk, 0, stream>>>(va, Wa1b, Wa2b, Wgbb, Wgcb, Wab, Wac,
                                  Sa, Gb, Gc, proj_ab, proj_ac);
  k_attend_mfma<2, 128><<<1024, blk, 0, stream>>>(vb, W1b_b, W2b_b, wv_b,
                                                  proj_ab, Gb, Sb);
  k_attend_mfma<4, 64><<<4096, blk, 0, stream>>>(vc, W1b_c, W2b_c, wv_c,
                                                 proj_ac, Gc, Sc);
  k_final<<<512, blk, 0, stream>>>(Sb, Sc, Sa, Wr1b, Wr2b, out);
}

// Round 4
// 627.768 us; speedup vs baseline: 1.9511x; 1.0628x over previous
//
#include <hip/hip_runtime.h>
#include <hip/hip_bf16.h>

// Problem constants
// B=8, H=W=64, N=4096, VA_IN=256, VB_IN=128, VC_IN=64, VOUT=128, R0=2, R1=4
// LDS pitch rule: pitch in 4B words must be == 2 (mod 32) -> 2-way conflicts (free).
// 132 shorts = 66 words; 260 shorts = 130 words.

typedef __attribute__((ext_vector_type(8))) short bhalf8;
typedef __attribute__((ext_vector_type(4))) float f32x4;

__device__ __forceinline__ unsigned short f2b(float f) {
  union { float f; unsigned u; } v; v.f = f;
  unsigned r = v.u + 0x7FFFu + ((v.u >> 16) & 1u);  // RNE
  return (unsigned short)(r >> 16);
}
__device__ __forceinline__ float b2f(unsigned short h) {
  union { unsigned u; float f; } v; v.u = ((unsigned)h) << 16;
  return v.f;
}
__device__ __forceinline__ unsigned pk2(float a, float b) {
  return (unsigned)f2b(a) | ((unsigned)f2b(b) << 16);
}

// ---------------------------------------------------------------------------
// Prep: convert all weights to bf16; compute wv = W2^T . Wrw[128:]
// ---------------------------------------------------------------------------
__global__ __launch_bounds__(256) void k_prep_all(
    const float* __restrict__ Wa1, const float* __restrict__ Wa2,
    const float* __restrict__ Wgb, const float* __restrict__ Wgc,
    const float* __restrict__ Wb1, const float* __restrict__ Wb2,
    const float* __restrict__ Wc1, const float* __restrict__ Wc2,
    const float* __restrict__ Wr1, const float* __restrict__ Wr2,
    const float* __restrict__ Wab, const float* __restrict__ Wac,
    unsigned short* __restrict__ Wa1b, unsigned short* __restrict__ Wa2b,
    unsigned short* __restrict__ Wgbb, unsigned short* __restrict__ Wgcb,
    unsigned short* __restrict__ W1b_b, unsigned short* __restrict__ W2b_b,
    unsigned short* __restrict__ W1b_c, unsigned short* __restrict__ W2b_c,
    unsigned short* __restrict__ Wr1b, unsigned short* __restrict__ Wr2b,
    float* __restrict__ wv_b, float* __restrict__ wv_c) {
  const float* srcs[10] = {Wa1, Wa2, Wgb, Wgc, Wb1, Wb2, Wc1, Wc2, Wr1, Wr2};
  unsigned short* dsts[10] = {Wa1b, Wa2b, Wgbb, Wgcb, W1b_b, W2b_b, W1b_c, W2b_c, Wr1b, Wr2b};
  const int sizes[10] = {32768, 16384, 32768, 32768, 16384, 16384, 8192, 16384, 98304, 65536};
  int gid = blockIdx.x * 256 + threadIdx.x;
  int stride = gridDim.x * 256;
#pragma unroll
  for (int s = 0; s < 10; ++s)
    for (int i = gid; i < sizes[s]; i += stride) dsts[s][i] = f2b(srcs[s][i]);
  if (blockIdx.x == 0) {
    int u = threadIdx.x;
    if (u < 128) {
      float s = 0.f;
      for (int c = 0; c < 128; ++c) s += Wab[128 + c] * Wb2[c * 128 + u];
      wv_b[u] = s;
    } else {
      int v = u - 128;
      float s = 0.f;
      for (int c = 0; c < 128; ++c) s += Wac[128 + c] * Wc2[c * 128 + v];
      wv_c[v] = s;
    }
  }
}

// ---------------------------------------------------------------------------
// embA (MFMA): H=relu(Wa1@X); gates=1-sigmoid(Wg@X); E=Wa2@H; proj=Wab.E;
// Sa = sigmoid(E). Outputs token-major bf16. 64 tokens/block.
// ---------------------------------------------------------------------------
__global__ __launch_bounds__(256) void k_embA(
    const float* __restrict__ va,
    const unsigned short* __restrict__ Wa1b, const unsigned short* __restrict__ Wa2b,
    const unsigned short* __restrict__ Wgbb, const unsigned short* __restrict__ Wgcb,
    const float* __restrict__ Wab, const float* __restrict__ Wac,
    unsigned short* __restrict__ Sa, unsigned short* __restrict__ Gb,
    unsigned short* __restrict__ Gc,
    float* __restrict__ proj_ab, float* __restrict__ proj_ac) {
  constexpr int PX = 260, PHp = 132;
  __shared__ unsigned short Xs[64 * PX];   // 33.3 KB
  __shared__ unsigned short Hs[64 * PHp];  // 16.9 KB
  __shared__ float wabl[128], wacl[128];
  const int u = threadIdx.x;
  const int b = blockIdx.x >> 6, tile = blockIdx.x & 63;
  const int n0 = tile * 64;

  if (u < 128) wabl[u] = Wab[u];
  else wacl[u - 128] = Wac[u - 128];

  // stage X tile (256 ch x 64 tok) -> bf16 LDS [col][k]
  const float* xb = va + (size_t)b * 256 * 4096 + n0;
#pragma unroll
  for (int it = 0; it < 32; ++it) {
    int idx = it * 256 + u;
    int chp = idx >> 6, t = idx & 63;
    float f0 = xb[(size_t)(2 * chp) * 4096 + t];
    float f1 = xb[(size_t)(2 * chp + 1) * 4096 + t];
    *(unsigned*)(Xs + t * PX + 2 * chp) = pk2(f0, f1);
  }
  __syncthreads();

  const int wave = u >> 6, lane = u & 63, quad = lane >> 4, ln = lane & 15;
  const int col = wave * 16 + ln;
  const size_t tok = (size_t)(b * 4096 + n0 + col);

  bhalf8 bx[8];
#pragma unroll
  for (int ks = 0; ks < 8; ++ks)
    bx[ks] = *(const bhalf8*)(Xs + col * PX + ks * 32 + quad * 8);

  f32x4 acc[8];
  // ---- H = relu(Wa1 @ X) -> Hs (wave-local cols) ----
#pragma unroll
  for (int rt = 0; rt < 8; ++rt) acc[rt] = (f32x4)(0.f);
#pragma unroll
  for (int rt = 0; rt < 8; ++rt)
#pragma unroll
    for (int ks = 0; ks < 8; ++ks) {
      bhalf8 af = *(const bhalf8*)((const short*)Wa1b + (rt * 16 + ln) * 256 + ks * 32 + quad * 8);
      acc[rt] = __builtin_amdgcn_mfma_f32_16x16x32_bf16(af, bx[ks], acc[rt], 0, 0, 0);
    }
#pragma unroll
  for (int rt = 0; rt < 8; ++rt) {
    f32x4 v = acc[rt];
    uint2 p;
    p.x = pk2(fmaxf(v.x, 0.f), fmaxf(v.y, 0.f));
    p.y = pk2(fmaxf(v.z, 0.f), fmaxf(v.w, 0.f));
    *(uint2*)(Hs + col * PHp + rt * 16 + quad * 4) = p;
  }

  // ---- gate_b = 1/(1+exp(Wgb @ X)) ----
#pragma unroll
  for (int rt = 0; rt < 8; ++rt) acc[rt] = (f32x4)(0.f);
#pragma unroll
  for (int rt = 0; rt < 8; ++rt)
#pragma unroll
    for (int ks = 0; ks < 8; ++ks) {
      bhalf8 af = *(const bhalf8*)((const short*)Wgbb + (rt * 16 + ln) * 256 + ks * 32 + quad * 8);
      acc[rt] = __builtin_amdgcn_mfma_f32_16x16x32_bf16(af, bx[ks], acc[rt], 0, 0, 0);
    }
#pragma unroll
  for (int rt = 0; rt < 8; ++rt) {
    f32x4 v = acc[rt];
    uint2 p;
    p.x = pk2(1.f / (1.f + expf(v.x)), 1.f / (1.f + expf(v.y)));
    p.y = pk2(1.f / (1.f + expf(v.z)), 1.f / (1.f + expf(v.w)));
    *(uint2*)(Gb + tok * 128 + rt * 16 + quad * 4) = p;
  }

  // ---- gate_c ----
#pragma unroll
  for (int rt = 0; rt < 8; ++rt) acc[rt] = (f32x4)(0.f);
#pragma unroll
  for (int rt = 0; rt < 8; ++rt)
#pragma unroll
    for (int ks = 0; ks < 8; ++ks) {
      bhalf8 af = *(const bhalf8*)((const short*)Wgcb + (rt * 16 + ln) * 256 + ks * 32 + quad * 8);
      acc[rt] = __builtin_amdgcn_mfma_f32_16x16x32_bf16(af, bx[ks], acc[rt], 0, 0, 0);
    }
#pragma unroll
  for (int rt = 0; rt < 8; ++rt) {
    f32x4 v = acc[rt];
    uint2 p;
    p.x = pk2(1.f / (1.f + expf(v.x)), 1.f / (1.f + expf(v.y)));
    p.y = pk2(1.f / (1.f + expf(v.z)), 1.f / (1.f + expf(v.w)));
    *(uint2*)(Gc + tok * 128 + rt * 16 + quad * 4) = p;
  }

  // ---- E = Wa2 @ H (wave-local, no barrier needed) ----
  bhalf8 bh[4];
#pragma unroll
  for (int ks = 0; ks < 4; ++ks)
    bh[ks] = *(const bhalf8*)(Hs + col * PHp + ks * 32 + quad * 8);
#pragma unroll
  for (int rt = 0; rt < 8; ++rt) acc[rt] = (f32x4)(0.f);
#pragma unroll
  for (int rt = 0; rt < 8; ++rt)
#pragma unroll
    for (int ks = 0; ks < 4; ++ks) {
      bhalf8 af = *(const bhalf8*)((const short*)Wa2b + (rt * 16 + ln) * 128 + ks * 32 + quad * 8);
      acc[rt] = __builtin_amdgcn_mfma_f32_16x16x32_bf16(af, bh[ks], acc[rt], 0, 0, 0);
    }

  // proj + Sa = sigmoid(E)
  float pab = 0.f, pac = 0.f;
#pragma unroll
  for (int rt = 0; rt < 8; ++rt) {
    f32x4 v = acc[rt];
#pragma unroll
    for (int i = 0; i < 4; ++i) {
      float e = v[i];
      pab += wabl[rt * 16 + quad * 4 + i] * e;
      pac += wacl[rt * 16 + quad * 4 + i] * e;
    }
    uint2 p;
    p.x = pk2(1.f / (1.f + expf(-v.x)), 1.f / (1.f + expf(-v.y)));
    p.y = pk2(1.f / (1.f + expf(-v.z)), 1.f / (1.f + expf(-v.w)));
    *(uint2*)(Sa + tok * 128 + rt * 16 + quad * 4) = p;
  }
  pab += __shfl_xor(pab, 16, 64);
  pab += __shfl_xor(pab, 32, 64);
  pac += __shfl_xor(pac, 16, 64);
  pac += __shfl_xor(pac, 32, 64);
  if (lane < 16) {
    proj_ab[b * 4096 + n0 + col] = pab;
    proj_ac[b * 4096 + n0 + col] = pac;
  }
}

// ---------------------------------------------------------------------------
// MFMA attend: unfold -> MLP -> logit -> softmax over patches -> gated sum ->
// sigmoid -> token-major bf16 output. Single overlaid LDS buffer (V/H/E):
// each wave touches only its own 32 columns for V-frag/H/E, register-buffered
// before each overlay, so no extra barriers are needed.
// ---------------------------------------------------------------------------
template <int R, int KIN>
__global__ __launch_bounds__(256) void k_attend_mfma(
    const float* __restrict__ vsrc,            // [B][KIN][64R][64R]
    const unsigned short* __restrict__ W1b,    // [128][KIN] bf16
    const unsigned short* __restrict__ W2b,    // [128][128] bf16
    const float* __restrict__ wv,              // [128] = W2^T . Wrw_p
    const float* __restrict__ proj,            // [B][4096]
    const unsigned short* __restrict__ gate,   // [B][4096][128] bf16
    unsigned short* __restrict__ outS) {       // [B][4096][128] bf16
  constexpr int P = R * R;
  constexpr int T = 128 / P;
  constexpr int K1 = KIN / 32;
  constexpr int PH = 132;  // 66 words == 2 mod 32
  constexpr int HR = 64 * R;
  constexpr int TILES = 4096 / T;

  __shared__ unsigned short smem[128 * PH];  // 33.8 KB: V -> H -> E overlay
  __shared__ float s_logit[128];
  __shared__ float s_wgt[128];

  const int u = threadIdx.x;
  const int b = blockIdx.x / TILES;
  const int tile = blockIdx.x % TILES;
  const int n0 = tile * T;
  const int h = n0 >> 6, w0 = n0 & 63;
  const size_t HRW = (size_t)HR * HR;
  const float* vb = vsrc + (size_t)b * KIN * HRW;

  // ---- stage V tile as bf16 [col][k], pitch PH ----
#pragma unroll
  for (int i = 0; i < KIN / 4; ++i) {
    int idx = i * 256 + u;
    int col = idx & 127;
    int kp = idx >> 7;
    int t = col / P, r = col & (P - 1);
    int kh = r / R, kw = r & (R - 1);
    int hp = h * R + kh;
    int wp = (w0 + t) * R + kw;
    size_t base = (size_t)(2 * kp) * HRW + (size_t)hp * HR + wp;
    float f0 = vb[base];
    float f1 = vb[base + HRW];
    *(unsigned*)(smem + col * PH + 2 * kp) = pk2(f0, f1);
  }
  __syncthreads();

  const int wave = u >> 6, lane = u & 63, quad = lane >> 4, ln = lane & 15;

  // ---- load B-fragments for layer 1 (wave's own 32 cols) ----
  bhalf8 bf1[2][K1];
#pragma unroll
  for (int c2 = 0; c2 < 2; ++c2) {
    int col = wave * 32 + c2 * 16 + ln;
#pragma unroll
    for (int ks = 0; ks < K1; ++ks)
      bf1[c2][ks] = *(const bhalf8*)(smem + col * PH + ks * 32 + quad * 8);
  }
  f32x4 acc[8][2];
#pragma unroll
  for (int rt = 0; rt < 8; ++rt)
#pragma unroll
    for (int c2 = 0; c2 < 2; ++c2) acc[rt][c2] = (f32x4)(0.f);
#pragma unroll
  for (int rt = 0; rt < 8; ++rt) {
    bhalf8 af[K1];
#pragma unroll
    for (int ks = 0; ks < K1; ++ks)
      af[ks] = *(const bhalf8*)((const short*)W1b + (rt * 16 + ln) * KIN + ks * 32 + quad * 8);
#pragma unroll
    for (int c2 = 0; c2 < 2; ++c2)
#pragma unroll
      for (int ks = 0; ks < K1; ++ks)
        acc[rt][c2] = __builtin_amdgcn_mfma_f32_16x16x32_bf16(af[ks], bf1[c2][ks],
                                                              acc[rt][c2], 0, 0, 0);
  }
  // H overlay (own cols; V already consumed into bf1)
#pragma unroll
  for (int rt = 0; rt < 8; ++rt)
#pragma unroll
    for (int c2 = 0; c2 < 2; ++c2) {
      int col = wave * 32 + c2 * 16 + ln;
      int k = rt * 16 + quad * 4;
      f32x4 v = acc[rt][c2];
      uint2 p;
      p.x = pk2(fmaxf(v.x, 0.f), fmaxf(v.y, 0.f));
      p.y = pk2(fmaxf(v.z, 0.f), fmaxf(v.w, 0.f));
      *(uint2*)(smem + col * PH + k) = p;
    }

  // ---- wave-local logit: 2 lanes per col, 64 k each ----
  {
    int cloc = lane >> 1, half = lane & 1;
    int col = wave * 32 + cloc;
    float s = 0.f;
#pragma unroll 8
    for (int k = 0; k < 64; k += 2) {
      unsigned pkv = *(const unsigned*)(smem + col * PH + half * 64 + k);
      s += wv[half * 64 + k] * b2f((unsigned short)pkv) +
           wv[half * 64 + k + 1] * b2f((unsigned short)(pkv >> 16));
    }
    s += __shfl_xor(s, 1, 64);
    if (half == 0) {
      float pa = proj[b * 4096 + n0 + col / P];
      s_logit[col] = fmaxf(s + pa, 0.f);
    }
  }

  // ---- layer 2 ----
  bhalf8 bf2[2][4];
#pragma unroll
  for (int c2 = 0; c2 < 2; ++c2) {
    int col = wave * 32 + c2 * 16 + ln;
#pragma unroll
    for (int ks = 0; ks < 4; ++ks)
      bf2[c2][ks] = *(const bhalf8*)(smem + col * PH + ks * 32 + quad * 8);
  }
#pragma unroll
  for (int rt = 0; rt < 8; ++rt)
#pragma unroll
    for (int c2 = 0; c2 < 2; ++c2) acc[rt][c2] = (f32x4)(0.f);
#pragma unroll
  for (int rt = 0; rt < 8; ++rt) {
    bhalf8 af[4];
#pragma unroll
    for (int ks = 0; ks < 4; ++ks)
      af[ks] = *(const bhalf8*)((const short*)W2b + (rt * 16 + ln) * 128 + ks * 32 + quad * 8);
#pragma unroll
    for (int c2 = 0; c2 < 2; ++c2)
#pragma unroll
      for (int ks = 0; ks < 4; ++ks)
        acc[rt][c2] = __builtin_amdgcn_mfma_f32_16x16x32_bf16(af[ks], bf2[c2][ks],
                                                              acc[rt][c2], 0, 0, 0);
  }
  // E overlay (own cols; H consumed into bf2 + logit)
#pragma unroll
  for (int rt = 0; rt < 8; ++rt)
#pragma unroll
    for (int c2 = 0; c2 < 2; ++c2) {
      int col = wave * 32 + c2 * 16 + ln;
      int k = rt * 16 + quad * 4;
      f32x4 v = acc[rt][c2];
      uint2 p;
      p.x = pk2(v.x, v.y);
      p.y = pk2(v.z, v.w);
      *(uint2*)(smem + col * PH + k) = p;
    }
  __syncthreads();

  // ---- softmax over patches ----
  if (u < T) {
    float e[P];
    float mx = -INFINITY;
#pragma unroll
    for (int r = 0; r < P; ++r) {
      e[r] = s_logit[u * P + r];
      mx = fmaxf(mx, e[r]);
    }
    float s = 0.f;
#pragma unroll
    for (int r = 0; r < P; ++r) {
      e[r] = expf(e[r] - mx);
      s += e[r];
    }
    float inv = 1.f / s;
#pragma unroll
    for (int r = 0; r < P; ++r) s_wgt[u * P + r] = e[r] * inv;
  }
  __syncthreads();

  // ---- gated weighted sum + sigmoid -> token-major bf16 ----
  constexpr int ITER2 = (T * 64) / 256;
#pragma unroll
  for (int i = 0; i < ITER2; ++i) {
    int idx = i * 256 + u;
    int cp = idx & 63;
    int t = idx >> 6;
    float s0 = 0.f, s1 = 0.f;
#pragma unroll
    for (int r = 0; r < P; ++r) {
      float w = s_wgt[t * P + r];
      unsigned pkv = *(const unsigned*)(smem + (t * P + r) * PH + 2 * cp);
      s0 += w * b2f((unsigned short)pkv);
      s1 += w * b2f((unsigned short)(pkv >> 16));
    }
    size_t tok = (size_t)(b * 4096 + n0 + t);
    unsigned gk = *(const unsigned*)(gate + tok * 128 + 2 * cp);
    float v0 = s0 * b2f((unsigned short)gk);
    float v1 = s1 * b2f((unsigned short)(gk >> 16));
    *(unsigned*)(outS + tok * 128 + 2 * cp) =
        pk2(1.f / (1.f + expf(-v0)), 1.f / (1.f + expf(-v1)));
  }
}

// ---------------------------------------------------------------------------
// Final (MFMA): S=[Sb|Sc|Sa] token-major bf16 (K=384); Y=relu(Wr1@S);
// out = Wr2 @ Y. 64 tokens/block, wave-local Y in LDS.
// ---------------------------------------------------------------------------
__global__ __launch_bounds__(256) void k_final(
    const unsigned short* __restrict__ Sb, const unsigned short* __restrict__ Sc,
    const unsigned short* __restrict__ Sa,
    const unsigned short* __restrict__ Wr1b, const unsigned short* __restrict__ Wr2b,
    float* __restrict__ out) {
  constexpr int PY = 260;
  __shared__ unsigned short Ys[64 * PY];  // 33.3 KB
  const int u = threadIdx.x;
  const int b = blockIdx.x >> 6, tile = blockIdx.x & 63;
  const int n0 = tile * 64;
  const int wave = u >> 6, lane = u & 63, quad = lane >> 4, ln = lane & 15;
  const int col = wave * 16 + ln;
  const size_t tok = (size_t)(b * 4096 + n0 + col);

  bhalf8 bs[12];
#pragma unroll
  for (int ks = 0; ks < 12; ++ks) {
    const unsigned short* S = (ks < 4) ? Sb : ((ks < 8) ? Sc : Sa);
    bs[ks] = *(const bhalf8*)(S + tok * 128 + (ks & 3) * 32 + quad * 8);
  }

  f32x4 acc[16];
#pragma unroll
  for (int rt = 0; rt < 16; ++rt) acc[rt] = (f32x4)(0.f);
#pragma unroll
  for (int rt = 0; rt < 16; ++rt)
#pragma unroll
    for (int ks = 0; ks < 12; ++ks) {
      bhalf8 af = *(const bhalf8*)((const short*)Wr1b + (rt * 16 + ln) * 384 + ks * 32 + quad * 8);
      acc[rt] = __builtin_amdgcn_mfma_f32_16x16x32_bf16(af, bs[ks], acc[rt], 0, 0, 0);
    }
#pragma unroll
  for (int rt = 0; rt < 16; ++rt) {
    f32x4 v = acc[rt];
    uint2 p;
    p.x = pk2(fmaxf(v.x, 0.f), fmaxf(v.y, 0.f));
    p.y = pk2(fmaxf(v.z, 0.f), fmaxf(v.w, 0.f));
    *(uint2*)(Ys + col * PY + rt * 16 + quad * 4) = p;
  }

  // wave-local: no barrier needed
  bhalf8 by[8];
#pragma unroll
  for (int ks = 0; ks < 8; ++ks)
    by[ks] = *(const bhalf8*)(Ys + col * PY + ks * 32 + quad * 8);
#pragma unroll
  for (int rt = 0; rt < 16; ++rt) acc[rt] = (f32x4)(0.f);
#pragma unroll
  for (int rt = 0; rt < 16; ++rt)
#pragma unroll
    for (int ks = 0; ks < 8; ++ks) {
      bhalf8 af = *(const bhalf8*)((const short*)Wr2b + (rt * 16 + ln) * 256 + ks * 32 + quad * 8);
      acc[rt] = __builtin_amdgcn_mfma_f32_16x16x32_bf16(af, by[ks], acc[rt], 0, 0, 0);
    }
#pragma unroll
  for (int rt = 0; rt < 16; ++rt) {
    f32x4 v = acc[rt];
#pragma unroll
    for (int i = 0; i < 4; ++i)
      out[((size_t)(b * 256 + rt * 16 + quad * 4 + i)) * 4096 + n0 + col] = v[i];
  }
}

extern "C" void kernel_launch(void* const* d_in, const int* in_sizes, int n_in,
                              void* d_out, int out_size, void* d_ws, size_t ws_size,
                              hipStream_t stream) {
  (void)in_sizes; (void)n_in; (void)out_size; (void)ws_size;
  const float* va  = (const float*)d_in[0];
  const float* vb  = (const float*)d_in[1];
  const float* vc  = (const float*)d_in[2];
  const float* Wa1 = (const float*)d_in[3];
  const float* Wa2 = (const float*)d_in[4];
  const float* Wgb = (const float*)d_in[5];
  const float* Wgc = (const float*)d_in[6];
  const float* Wb1 = (const float*)d_in[7];
  const float* Wb2 = (const float*)d_in[8];
  const float* Wc1 = (const float*)d_in[9];
  const float* Wc2 = (const float*)d_in[10];
  const float* Wab = (const float*)d_in[11];
  const float* Wac = (const float*)d_in[12];
  const float* Wr1 = (const float*)d_in[13];
  const float* Wr2 = (const float*)d_in[14];
  float* out = (float*)d_out;
  float* f = (float*)d_ws;

  const size_t SM = (size_t)8 * 4096 * 128 / 2;  // bf16 token-major array, in floats
  unsigned short* Sb = (unsigned short*)f; f += SM;
  unsigned short* Sc = (unsigned short*)f; f += SM;
  unsigned short* Sa = (unsigned short*)f; f += SM;
  unsigned short* Gb = (unsigned short*)f; f += SM;
  unsigned short* Gc = (unsigned short*)f; f += SM;
  float* proj_ab = f; f += 8 * 4096;
  float* proj_ac = f; f += 8 * 4096;
  float* wv_b = f; f += 128;
  float* wv_c = f; f += 128;
  unsigned short* Wa1b = (unsigned short*)f; f += 16384;
  unsigned short* Wa2b = (unsigned short*)f; f += 8192;
  unsigned short* Wgbb = (unsigned short*)f; f += 16384;
  unsigned short* Wgcb = (unsigned short*)f; f += 16384;
  unsigned short* W1b_b = (unsigned short*)f; f += 8192;
  unsigned short* W2b_b = (unsigned short*)f; f += 8192;
  unsigned short* W1b_c = (unsigned short*)f; f += 4096;
  unsigned short* W2b_c = (unsigned short*)f; f += 8192;
  unsigned short* Wr1b = (unsigned short*)f; f += 49152;
  unsigned short* Wr2b = (unsigned short*)f; f += 32768;

  dim3 blk(256);
  k_prep_all<<<120, blk, 0, stream>>>(Wa1, Wa2, Wgb, Wgc, Wb1, Wb2, Wc1, Wc2,
                                      Wr1, Wr2, Wab, Wac,
                                      Wa1b, Wa2b, Wgbb, Wgcb, W1b_b, W2b_b,
                                      W1b_c, W2b_c, Wr1b, Wr2b, wv_b, wv_c);
  k_embA<<<512, blk, 0, stream>>>(va, Wa1b, Wa2b, Wgbb, Wgcb, Wab, Wac,
                                  Sa, Gb, Gc, proj_ab, proj_ac);
  k_attend_mfma<2, 128><<<1024, blk, 0, stream>>>(vb, W1b_b, W2b_b, wv_b,
                                                  proj_ab, Gb, Sb);
  k_attend_mfma<4, 64><<<4096, blk, 0, stream>>>(vc, W1b_c, W2b_c, wv_c,
                                                 proj_ac, Gc, Sc);
  k_final<<<512, blk, 0, stream>>>(Sb, Sc, Sa, Wr1b, Wr2b, out);
}